// Round 5
// baseline (31.380 us; speedup 1.0000x reference)
//
#include <hip/hip_runtime.h>

// Reference reduces exactly to mean(where(up < 0.2, up, 0)):
// right2up == 0 identically (scatter-min of strictly-positive values into a
// zero buffer), pixel_diff = |up|, masked mean. Only d_in[0] (up) is read.
//
// DIAGNOSTIC ROUND: two-kernel structure (R1/R3 = 18.9/19.0 us), but with
// kernel1 dispatched TWICE (idempotent: same partials both times -> identical
// output, deterministic). dur_R5 - dur_R3 ~= k1_warm + node_gap, resolving
// whether the 19us is kernel1-BW-bound (k1~14-16) or node-overhead-bound
// (k1~11). Steers round 6.

#define RED_BLOCKS 2048
#define RED_THREADS 256
#define NT (RED_BLOCKS * RED_THREADS)   // 524,288 threads

__device__ __forceinline__ float mask_sum4(float4 v) {
    float x = fabsf(v.x), y = fabsf(v.y), z = fabsf(v.z), w = fabsf(v.w);
    return ((x < 0.2f) ? x : 0.f) + ((y < 0.2f) ? y : 0.f)
         + ((z < 0.2f) ? z : 0.f) + ((w < 0.2f) ? w : 0.f);
}

__global__ __launch_bounds__(RED_THREADS)
void closs_partial_kernel(const float* __restrict__ up, float* __restrict__ ws, int n4) {
    const float4* __restrict__ up4 = reinterpret_cast<const float4*>(up);
    const int tid = blockIdx.x * blockDim.x + threadIdx.x;

    float a0 = 0.f, a1 = 0.f, a2 = 0.f, a3 = 0.f;
    if (n4 == 8 * NT) {
        #pragma unroll
        for (int it = 0; it < 2; ++it) {
            float4 v0 = up4[tid + (it * 4 + 0) * NT];
            float4 v1 = up4[tid + (it * 4 + 1) * NT];
            float4 v2 = up4[tid + (it * 4 + 2) * NT];
            float4 v3 = up4[tid + (it * 4 + 3) * NT];
            a0 += mask_sum4(v0); a1 += mask_sum4(v1);
            a2 += mask_sum4(v2); a3 += mask_sum4(v3);
        }
    } else {
        for (int idx = tid; idx < n4; idx += NT) a0 += mask_sum4(up4[idx]);
    }
    float acc = (a0 + a1) + (a2 + a3);

    #pragma unroll
    for (int off = 32; off > 0; off >>= 1) acc += __shfl_down(acc, off, 64);
    __shared__ float sdata[RED_THREADS / 64];
    const int lane = threadIdx.x & 63;
    const int wid  = threadIdx.x >> 6;
    if (lane == 0) sdata[wid] = acc;
    __syncthreads();
    if (threadIdx.x == 0)
        ws[blockIdx.x] = (sdata[0] + sdata[1]) + (sdata[2] + sdata[3]);
}

__global__ __launch_bounds__(RED_THREADS)
void closs_final_kernel(const float* __restrict__ ws, float* __restrict__ out,
                        float inv_n) {
    float acc = 0.0f;
    #pragma unroll
    for (int k = 0; k < RED_BLOCKS / RED_THREADS; ++k)
        acc += ws[threadIdx.x + k * RED_THREADS];
    #pragma unroll
    for (int off = 32; off > 0; off >>= 1) acc += __shfl_down(acc, off, 64);
    __shared__ float sdata[RED_THREADS / 64];
    const int lane = threadIdx.x & 63;
    const int wid  = threadIdx.x >> 6;
    if (lane == 0) sdata[wid] = acc;
    __syncthreads();
    if (threadIdx.x == 0)
        out[0] = ((sdata[0] + sdata[1]) + (sdata[2] + sdata[3])) * inv_n;
}

extern "C" void kernel_launch(void* const* d_in, const int* in_sizes, int n_in,
                              void* d_out, int out_size, void* d_ws, size_t ws_size,
                              hipStream_t stream) {
    const float* up = (const float*)d_in[0];
    float* out = (float*)d_out;
    float* ws  = (float*)d_ws;   // RED_BLOCKS floats = 8 KiB

    const int n  = in_sizes[0];  // 64*1*512*512 = 16,777,216
    const int n4 = n >> 2;
    const float inv_n = 1.0f / (float)n;

    // kernel1 dispatched twice on purpose (diagnostic; idempotent writes)
    closs_partial_kernel<<<RED_BLOCKS, RED_THREADS, 0, stream>>>(up, ws, n4);
    closs_partial_kernel<<<RED_BLOCKS, RED_THREADS, 0, stream>>>(up, ws, n4);
    closs_final_kernel<<<1, RED_THREADS, 0, stream>>>(ws, out, inv_n);
}

// Round 6
// 20.747 us; speedup vs baseline: 1.5125x; 1.5125x over previous
//
#include <hip/hip_runtime.h>

// Reference reduces exactly to mean(where(up < 0.2, up, 0)):
// right2up == 0 identically (scatter-min of strictly-positive values into a
// zero-initialized buffer), pixel_diff = |up|, masked mean over all elements.
// Only d_in[0] (up) is read; left/right are dead.
//
// SINGLE graph node. Mailbox finalize, v2 (R4 post-mortem applied):
//  - block i publishes (MAGIC<<32 | float_bits) to its OWN slot via
//    atomicExch (device-scope, distinct addresses, no fence -- R2 showed
//    fences cost ~100us; R4 proved this publish correct).
//  - block 0 (first dispatched -> resident) polls with relaxed AGENT-scope
//    atomic LOADS (no RMW serialization -- R4's poll cost) in sleep-throttled
//    sweeps, sums in FIXED index order (bit-deterministic), writes out,
//    resets slots with relaxed agent stores.
//  - 0xAA poison top32 != MAGIC -> poisoned ws never fakes a partial.

#define RED_BLOCKS 2048
#define RED_THREADS 256
#define NT (RED_BLOCKS * RED_THREADS)               // 524,288 threads
#define SLOTS_PER_THREAD (RED_BLOCKS / RED_THREADS) // 8
#define MAGIC_HI 0x5A17C0DEu

__device__ __forceinline__ float mask_sum4(float4 v) {
    float x = fabsf(v.x), y = fabsf(v.y), z = fabsf(v.z), w = fabsf(v.w);
    return ((x < 0.2f) ? x : 0.f) + ((y < 0.2f) ? y : 0.f)
         + ((z < 0.2f) ? z : 0.f) + ((w < 0.2f) ? w : 0.f);
}

__global__ __launch_bounds__(RED_THREADS)
void closs_onepass2_kernel(const float* __restrict__ up, float* __restrict__ out,
                           unsigned long long* __restrict__ slots,
                           int n4, float inv_n) {
    const float4* __restrict__ up4 = reinterpret_cast<const float4*>(up);
    const int tid = blockIdx.x * blockDim.x + threadIdx.x;

    float a0 = 0.f, a1 = 0.f, a2 = 0.f, a3 = 0.f;
    if (n4 == 8 * NT) {
        #pragma unroll
        for (int it = 0; it < 2; ++it) {
            float4 v0 = up4[tid + (it * 4 + 0) * NT];
            float4 v1 = up4[tid + (it * 4 + 1) * NT];
            float4 v2 = up4[tid + (it * 4 + 2) * NT];
            float4 v3 = up4[tid + (it * 4 + 3) * NT];
            a0 += mask_sum4(v0); a1 += mask_sum4(v1);
            a2 += mask_sum4(v2); a3 += mask_sum4(v3);
        }
    } else {
        for (int idx = tid; idx < n4; idx += NT) a0 += mask_sum4(up4[idx]);
    }
    float acc = (a0 + a1) + (a2 + a3);

    #pragma unroll
    for (int off = 32; off > 0; off >>= 1) acc += __shfl_down(acc, off, 64);
    __shared__ float sdata[RED_THREADS / 64];
    const int lane = threadIdx.x & 63, wid = threadIdx.x >> 6;
    if (lane == 0) sdata[wid] = acc;
    __syncthreads();

    if (threadIdx.x == 0) {
        float s = (sdata[0] + sdata[1]) + (sdata[2] + sdata[3]);
        unsigned long long payload =
            ((unsigned long long)MAGIC_HI << 32) | (unsigned long long)__float_as_uint(s);
        atomicExch(&slots[blockIdx.x], payload);   // device-scope publish
    }

    if (blockIdx.x != 0) return;   // 2047 blocks publish and exit

    // ---- block 0: gather 2048 partials (8 per thread) ----
    __syncthreads();   // protect sdata reuse (phase-1 reader vs phase-2 writers)

    const int base = threadIdx.x * SLOTS_PER_THREAD;
    float vals[SLOTS_PER_THREAD];
    unsigned ready = 0;
    while (ready != (1u << SLOTS_PER_THREAD) - 1u) {
        #pragma unroll
        for (int k = 0; k < SLOTS_PER_THREAD; ++k) {
            if (!(ready & (1u << k))) {
                unsigned long long v = __hip_atomic_load(
                    &slots[base + k], __ATOMIC_RELAXED, __HIP_MEMORY_SCOPE_AGENT);
                if ((unsigned)(v >> 32) == MAGIC_HI) {
                    vals[k] = __uint_as_float((unsigned)(v & 0xFFFFFFFFull));
                    ready |= 1u << k;
                }
            }
        }
        if (ready != (1u << SLOTS_PER_THREAD) - 1u)
            __builtin_amdgcn_s_sleep(16);   // ~1024 cyc: throttle re-sweeps
    }

    // fixed-order deterministic final sum
    float f = ((vals[0] + vals[1]) + (vals[2] + vals[3]))
            + ((vals[4] + vals[5]) + (vals[6] + vals[7]));
    #pragma unroll
    for (int off = 32; off > 0; off >>= 1) f += __shfl_down(f, off, 64);
    if (lane == 0) sdata[wid] = f;
    __syncthreads();
    if (threadIdx.x == 0)
        out[0] = ((sdata[0] + sdata[1]) + (sdata[2] + sdata[3])) * inv_n;

    // reset own slots for the next replay (relaxed agent stores, parallel)
    #pragma unroll
    for (int k = 0; k < SLOTS_PER_THREAD; ++k)
        __hip_atomic_store(&slots[base + k], 0ull,
                           __ATOMIC_RELAXED, __HIP_MEMORY_SCOPE_AGENT);
}

extern "C" void kernel_launch(void* const* d_in, const int* in_sizes, int n_in,
                              void* d_out, int out_size, void* d_ws, size_t ws_size,
                              hipStream_t stream) {
    const float* up = (const float*)d_in[0];
    float* out = (float*)d_out;
    unsigned long long* slots = (unsigned long long*)d_ws;  // 2048 * 8 B = 16 KiB

    const int n  = in_sizes[0];   // 64*1*512*512 = 16,777,216
    const int n4 = n >> 2;
    const float inv_n = 1.0f / (float)n;

    closs_onepass2_kernel<<<RED_BLOCKS, RED_THREADS, 0, stream>>>(up, out, slots, n4, inv_n);
}

// Round 7
// 16.703 us; speedup vs baseline: 1.8787x; 1.2421x over previous
//
#include <hip/hip_runtime.h>

// Reference reduces exactly to mean(where(up < 0.2, up, 0)):
// right2up == 0 identically (scatter-min of strictly-positive values into a
// zero-initialized buffer), pixel_diff = |up|, masked mean over all elements.
// Only d_in[0] (up) is read; left/right are dead.
//
// SINGLE graph node. Mailbox v3 (R6 post-mortem: detection latency was the
// tail, 8 serial loads/thread + 0.43us sleep quantum):
//  - 512 blocks x 1024 threads (same 524,288 threads, 32 waves/CU; entire
//    grid co-resident (2 blocks/CU) -> spin provably deadlock-free).
//  - block i publishes (MAGIC<<32 | float_bits) to its OWN slot via
//    atomicExch (distinct addresses -- R2 showed same-address RMW serializes
//    ~50ns/op; R4/R6 proved this publish correct).
//  - block 0: threads 0..511 each spin on ONE slot with dependent relaxed
//    agent-scope atomic loads (no sleep; self-throttled at load latency).
//    Fixed-order final sum (bit-deterministic), reset via relaxed stores.
//  - 0xAA poison top32 != MAGIC -> poisoned ws never fakes a partial.

#define RED_BLOCKS 512
#define RED_THREADS 1024
#define NT (RED_BLOCKS * RED_THREADS)   // 524,288 threads
#define NWAVES (RED_THREADS / 64)       // 16
#define MAGIC_HI 0x5A17C0DEu

__device__ __forceinline__ float mask_sum4(float4 v) {
    float x = fabsf(v.x), y = fabsf(v.y), z = fabsf(v.z), w = fabsf(v.w);
    return ((x < 0.2f) ? x : 0.f) + ((y < 0.2f) ? y : 0.f)
         + ((z < 0.2f) ? z : 0.f) + ((w < 0.2f) ? w : 0.f);
}

__global__ __launch_bounds__(RED_THREADS)
void closs_onepass3_kernel(const float* __restrict__ up, float* __restrict__ out,
                           unsigned long long* __restrict__ slots,
                           int n4, float inv_n) {
    const float4* __restrict__ up4 = reinterpret_cast<const float4*>(up);
    const int tid = blockIdx.x * blockDim.x + threadIdx.x;

    float a0 = 0.f, a1 = 0.f, a2 = 0.f, a3 = 0.f;
    if (n4 == 8 * NT) {
        #pragma unroll
        for (int it = 0; it < 2; ++it) {
            float4 v0 = up4[tid + (it * 4 + 0) * NT];
            float4 v1 = up4[tid + (it * 4 + 1) * NT];
            float4 v2 = up4[tid + (it * 4 + 2) * NT];
            float4 v3 = up4[tid + (it * 4 + 3) * NT];
            a0 += mask_sum4(v0); a1 += mask_sum4(v1);
            a2 += mask_sum4(v2); a3 += mask_sum4(v3);
        }
    } else {
        for (int idx = tid; idx < n4; idx += NT) a0 += mask_sum4(up4[idx]);
    }
    float acc = (a0 + a1) + (a2 + a3);

    // in-block deterministic reduce: wave shuffle + fixed-order LDS combine
    #pragma unroll
    for (int off = 32; off > 0; off >>= 1) acc += __shfl_down(acc, off, 64);
    __shared__ float sdata[NWAVES];
    const int lane = threadIdx.x & 63, wid = threadIdx.x >> 6;
    if (lane == 0) sdata[wid] = acc;
    __syncthreads();

    if (threadIdx.x == 0) {
        float s = 0.f;
        #pragma unroll
        for (int w = 0; w < NWAVES; ++w) s += sdata[w];
        unsigned long long payload =
            ((unsigned long long)MAGIC_HI << 32) | (unsigned long long)__float_as_uint(s);
        atomicExch(&slots[blockIdx.x], payload);   // device-scope publish
    }

    if (blockIdx.x != 0) return;   // 511 blocks publish and exit

    // ---- block 0: one slot per thread, dependent-load spin ----
    __syncthreads();   // sdata reuse barrier (all 1024 threads participate)

    float pv = 0.f;
    if (threadIdx.x < RED_BLOCKS) {
        unsigned long long v;
        do {
            v = __hip_atomic_load(&slots[threadIdx.x],
                                  __ATOMIC_RELAXED, __HIP_MEMORY_SCOPE_AGENT);
        } while ((unsigned)(v >> 32) != MAGIC_HI);
        pv = __uint_as_float((unsigned)(v & 0xFFFFFFFFull));
    }

    #pragma unroll
    for (int off = 32; off > 0; off >>= 1) pv += __shfl_down(pv, off, 64);
    if (lane == 0) sdata[wid] = pv;
    __syncthreads();
    if (threadIdx.x == 0) {
        float t = 0.f;
        #pragma unroll
        for (int w = 0; w < NWAVES; ++w) t += sdata[w];   // fixed order
        out[0] = t * inv_n;
    }

    // reset slots for next replay (relaxed agent stores, one per thread)
    if (threadIdx.x < RED_BLOCKS)
        __hip_atomic_store(&slots[threadIdx.x], 0ull,
                           __ATOMIC_RELAXED, __HIP_MEMORY_SCOPE_AGENT);
}

extern "C" void kernel_launch(void* const* d_in, const int* in_sizes, int n_in,
                              void* d_out, int out_size, void* d_ws, size_t ws_size,
                              hipStream_t stream) {
    const float* up = (const float*)d_in[0];
    float* out = (float*)d_out;
    unsigned long long* slots = (unsigned long long*)d_ws;  // 512 * 8 B = 4 KiB

    const int n  = in_sizes[0];   // 64*1*512*512 = 16,777,216
    const int n4 = n >> 2;
    const float inv_n = 1.0f / (float)n;

    closs_onepass3_kernel<<<RED_BLOCKS, RED_THREADS, 0, stream>>>(up, out, slots, n4, inv_n);
}